// Round 1
// baseline (55.451 us; speedup 1.0000x reference)
//
#include <hip/hip_runtime.h>

#define NROWS 32768
#define DDIM  512

__global__ void zero_out_kernel(float* out) {
    out[0] = 0.0f;
}

__global__ __launch_bounds__(256) void dotloss_kernel(
    const float* __restrict__ img,
    const float* __restrict__ aud,
    const int*   __restrict__ iimp,
    const int*   __restrict__ aimp,
    float* __restrict__ out)
{
    const int lane  = threadIdx.x & 63;
    const int wave  = threadIdx.x >> 6;          // 0..3
    const int wpb   = blockDim.x >> 6;           // waves per block
    const int gwave = blockIdx.x * wpb + wave;
    const int nwave = gridDim.x * wpb;

    float acc = 0.0f;

    for (int row = gwave; row < NROWS; row += nwave) {
        const int ii = iimp[row];
        const int ai = aimp[row];

        const float4* imR = (const float4*)(img + (size_t)row * DDIM);
        const float4* auR = (const float4*)(aud + (size_t)row * DDIM);
        const float4* imI = (const float4*)(img + (size_t)ii  * DDIM);
        const float4* auA = (const float4*)(aud + (size_t)ai  * DDIM);

        // 512 floats = 128 float4 per row; 64 lanes -> 2 float4/lane
        float4 a0 = imR[lane], a1 = imR[lane + 64];
        float4 b0 = auR[lane], b1 = auR[lane + 64];
        float4 c0 = imI[lane], c1 = imI[lane + 64];
        float4 d0 = auA[lane], d1 = auA[lane + 64];

        float anc = a0.x*b0.x + a0.y*b0.y + a0.z*b0.z + a0.w*b0.w
                  + a1.x*b1.x + a1.y*b1.y + a1.z*b1.z + a1.w*b1.w;
        float si  = c0.x*b0.x + c0.y*b0.y + c0.z*b0.z + c0.w*b0.w
                  + c1.x*b1.x + c1.y*b1.y + c1.z*b1.z + c1.w*b1.w;
        float sa  = a0.x*d0.x + a0.y*d0.y + a0.z*d0.z + a0.w*d0.w
                  + a1.x*d1.x + a1.y*d1.y + a1.z*d1.z + a1.w*d1.w;

        // 64-lane butterfly reduction of the three partials
        #pragma unroll
        for (int off = 32; off > 0; off >>= 1) {
            anc += __shfl_xor(anc, off, 64);
            si  += __shfl_xor(si,  off, 64);
            sa  += __shfl_xor(sa,  off, 64);
        }

        // all lanes hold full sums now; hinge loss
        float l = fmaxf(0.0f, 1.0f + si - anc) + fmaxf(0.0f, 1.0f + sa - anc);
        acc += l;
    }

    // per-block reduction: lane 0 of each wave contributes
    __shared__ float s[8];
    if (lane == 0) s[wave] = acc;
    __syncthreads();
    if (threadIdx.x == 0) {
        float t = 0.0f;
        for (int w = 0; w < wpb; ++w) t += s[w];
        atomicAdd(out, t * (1.0f / (float)NROWS));
    }
}

extern "C" void kernel_launch(void* const* d_in, const int* in_sizes, int n_in,
                              void* d_out, int out_size, void* d_ws, size_t ws_size,
                              hipStream_t stream) {
    const float* img  = (const float*)d_in[0];
    const float* aud  = (const float*)d_in[1];
    const int*   iimp = (const int*)d_in[2];
    const int*   aimp = (const int*)d_in[3];
    float* out = (float*)d_out;

    zero_out_kernel<<<1, 1, 0, stream>>>(out);

    const int blocks = 2048;           // 8192 waves, 4 rows per wave
    dotloss_kernel<<<blocks, 256, 0, stream>>>(img, aud, iimp, aimp, out);
}

// Round 2
// 55.391 us; speedup vs baseline: 1.0011x; 1.0011x over previous
//
#include <hip/hip_runtime.h>

#define NROWS 32768
#define DDIM  512

__global__ void zero_out_kernel(float* out) {
    out[0] = 0.0f;
}

// 16 lanes per row; 4 rows per wave; 16 rows per 256-thread block.
// Grid = NROWS/16 = 2048 blocks, exactly one row-iteration per wave.
__global__ __launch_bounds__(256, 8) void dotloss_kernel(
    const float* __restrict__ img,
    const float* __restrict__ aud,
    const int*   __restrict__ iimp,
    const int*   __restrict__ aimp,
    float* __restrict__ out)
{
    const int tid = threadIdx.x;
    const int g   = tid & 15;            // lane within 16-lane row group
    const int grp = tid >> 4;            // 0..15 row group within block
    const int row = (blockIdx.x << 4) + grp;

    const int ii = iimp[row];
    const int ai = aimp[row];

    const float4* __restrict__ imR = (const float4*)(img + (size_t)row * DDIM) + g;
    const float4* __restrict__ auR = (const float4*)(aud + (size_t)row * DDIM) + g;
    const float4* __restrict__ imI = (const float4*)(img + (size_t)ii  * DDIM) + g;
    const float4* __restrict__ auA = (const float4*)(aud + (size_t)ai  * DDIM) + g;

    // u = (img[ii] - img[row]) . aud[row]   -> Iimpsim - anchorsim
    // v = img[row] . (aud[ai] - aud[row])   -> Aimpsim - anchorsim
    float u0 = 0.f, u1 = 0.f, v0 = 0.f, v1 = 0.f;

    #pragma unroll
    for (int k = 0; k < 8; ++k) {
        float4 a = imR[16 * k];
        float4 b = auR[16 * k];
        float4 c = imI[16 * k];
        float4 d = auA[16 * k];
        u0 += (c.x - a.x) * b.x + (c.y - a.y) * b.y;
        u1 += (c.z - a.z) * b.z + (c.w - a.w) * b.w;
        v0 += a.x * (d.x - b.x) + a.y * (d.y - b.y);
        v1 += a.z * (d.z - b.z) + a.w * (d.w - b.w);
    }
    float u = u0 + u1;
    float v = v0 + v1;

    // reduce across the 16-lane group (xor butterfly stays within group)
    #pragma unroll
    for (int off = 1; off < 16; off <<= 1) {
        u += __shfl_xor(u, off, 64);
        v += __shfl_xor(v, off, 64);
    }

    float loss = fmaxf(0.f, 1.f + u) + fmaxf(0.f, 1.f + v);

    __shared__ float s[16];
    if (g == 0) s[grp] = loss;
    __syncthreads();
    if (tid == 0) {
        float t = 0.f;
        #pragma unroll
        for (int i = 0; i < 16; ++i) t += s[i];
        atomicAdd(out, t * (1.0f / (float)NROWS));
    }
}

extern "C" void kernel_launch(void* const* d_in, const int* in_sizes, int n_in,
                              void* d_out, int out_size, void* d_ws, size_t ws_size,
                              hipStream_t stream) {
    const float* img  = (const float*)d_in[0];
    const float* aud  = (const float*)d_in[1];
    const int*   iimp = (const int*)d_in[2];
    const int*   aimp = (const int*)d_in[3];
    float* out = (float*)d_out;

    zero_out_kernel<<<1, 1, 0, stream>>>(out);

    const int blocks = NROWS / 16;   // 2048
    dotloss_kernel<<<blocks, 256, 0, stream>>>(img, aud, iimp, aimp, out);
}

// Round 3
// 42.788 us; speedup vs baseline: 1.2960x; 1.2945x over previous
//
#include <hip/hip_runtime.h>

#define NROWS  32768
#define DDIM   512
#define BLOCKS 2048   // NROWS / 16 rows-per-block

// 16 lanes per row; 16 rows per 256-thread block. No atomics:
// per-block partial sums go to workspace, reduced by a second kernel.
__global__ __launch_bounds__(256) void dotloss_main(
    const float* __restrict__ img,
    const float* __restrict__ aud,
    const int*   __restrict__ iimp,
    const int*   __restrict__ aimp,
    float* __restrict__ partial)
{
    const int tid = threadIdx.x;
    const int g   = tid & 15;            // lane within 16-lane row group
    const int grp = tid >> 4;            // row group within block
    const int row = (blockIdx.x << 4) + grp;

    const int ii = iimp[row];
    const int ai = aimp[row];

    const float4* __restrict__ imR = (const float4*)(img + (size_t)row * DDIM) + g;
    const float4* __restrict__ auR = (const float4*)(aud + (size_t)row * DDIM) + g;
    const float4* __restrict__ imI = (const float4*)(img + (size_t)ii  * DDIM) + g;
    const float4* __restrict__ auA = (const float4*)(aud + (size_t)ai  * DDIM) + g;

    // u = (img[ii]-img[row]) . aud[row]  = Iimpsim - anchorsim
    // v = img[row] . (aud[ai]-aud[row])  = Aimpsim - anchorsim
    float u = 0.f, v = 0.f;

    #pragma unroll
    for (int k = 0; k < 8; ++k) {
        float4 a = imR[16 * k];
        float4 b = auR[16 * k];
        float4 c = imI[16 * k];
        float4 d = auA[16 * k];
        u += (c.x - a.x) * b.x + (c.y - a.y) * b.y
           + (c.z - a.z) * b.z + (c.w - a.w) * b.w;
        v += a.x * (d.x - b.x) + a.y * (d.y - b.y)
           + a.z * (d.z - b.z) + a.w * (d.w - b.w);
    }

    // reduce across the 16-lane group (xor butterfly stays within group)
    #pragma unroll
    for (int off = 1; off < 16; off <<= 1) {
        u += __shfl_xor(u, off, 64);
        v += __shfl_xor(v, off, 64);
    }

    float loss = fmaxf(0.f, 1.f + u) + fmaxf(0.f, 1.f + v);

    __shared__ float s[16];
    if (g == 0) s[grp] = loss;
    __syncthreads();
    if (tid == 0) {
        float t = 0.f;
        #pragma unroll
        for (int i = 0; i < 16; ++i) t += s[i];
        partial[blockIdx.x] = t;   // plain store, no atomic
    }
}

__global__ __launch_bounds__(256) void dotloss_reduce(
    const float* __restrict__ partial,
    float* __restrict__ out)
{
    const int tid = threadIdx.x;
    float t = 0.f;
    #pragma unroll
    for (int k = 0; k < BLOCKS / 256; ++k) t += partial[tid + 256 * k];

    #pragma unroll
    for (int off = 32; off > 0; off >>= 1) t += __shfl_xor(t, off, 64);

    __shared__ float s[4];
    if ((tid & 63) == 0) s[tid >> 6] = t;
    __syncthreads();
    if (tid == 0) out[0] = (s[0] + s[1] + s[2] + s[3]) * (1.0f / (float)NROWS);
}

extern "C" void kernel_launch(void* const* d_in, const int* in_sizes, int n_in,
                              void* d_out, int out_size, void* d_ws, size_t ws_size,
                              hipStream_t stream) {
    const float* img  = (const float*)d_in[0];
    const float* aud  = (const float*)d_in[1];
    const int*   iimp = (const int*)d_in[2];
    const int*   aimp = (const int*)d_in[3];
    float* out     = (float*)d_out;
    float* partial = (float*)d_ws;   // 2048 floats = 8 KB scratch

    dotloss_main<<<BLOCKS, 256, 0, stream>>>(img, aud, iimp, aimp, partial);
    dotloss_reduce<<<1, 256, 0, stream>>>(partial, out);
}